// Round 17
// baseline (25.122 us; speedup 1.0000x reference)
//
#include <hip/hip_runtime.h>
#include <math.h>

#define BATCH 4096
#define NPTS 1000

// Within-wave LDS producer->consumer fence (LDS ops are memory ops; the
// clobber orders them, sched_barrier stops migration).
#define WSYNC() do { asm volatile("s_waitcnt lgkmcnt(0)" ::: "memory"); \
                     __builtin_amdgcn_sched_barrier(0); } while (0)

// fast 1-ulp reciprocal (v_rcp_f32) — used only downstream of the knots
__device__ __forceinline__ float frcp(float v) { return __builtin_amdgcn_rcpf(v); }

// Full-wave (64-lane) sum via DPP — pure VALU, no LDS pipe (rocPRIM pattern).
// After the sequence lane 63 holds the total; readlane broadcasts it.
__device__ __forceinline__ float wave_sum64(float v) {
    int x = __float_as_int(v), y;
    y = __builtin_amdgcn_update_dpp(0, x, 0x111, 0xF, 0xF, true);   // row_shr:1
    x = __float_as_int(__int_as_float(x) + __int_as_float(y));
    y = __builtin_amdgcn_update_dpp(0, x, 0x112, 0xF, 0xF, true);   // row_shr:2
    x = __float_as_int(__int_as_float(x) + __int_as_float(y));
    y = __builtin_amdgcn_update_dpp(0, x, 0x114, 0xF, 0xF, true);   // row_shr:4
    x = __float_as_int(__int_as_float(x) + __int_as_float(y));
    y = __builtin_amdgcn_update_dpp(0, x, 0x118, 0xF, 0xF, true);   // row_shr:8
    x = __float_as_int(__int_as_float(x) + __int_as_float(y));
    y = __builtin_amdgcn_update_dpp(0, x, 0x142, 0xA, 0xF, false);  // row_bcast:15 -> rows 1,3
    x = __float_as_int(__int_as_float(x) + __int_as_float(y));
    y = __builtin_amdgcn_update_dpp(0, x, 0x143, 0xC, 0xF, false);  // row_bcast:31 -> rows 2,3
    x = __float_as_int(__int_as_float(x) + __int_as_float(y));
    return __int_as_float(__builtin_amdgcn_readlane(x, 63));        // uniform total
}

// ========== 16 elements/block, 1024 threads, 1 block/CU, W2 in LDS ==========
// r15 structure; M3 + eval reductions moved off the LDS pipe via DPP.
__global__ __launch_bounds__(1024, 4) void net2_one(
    const float* __restrict__ x, const float* __restrict__ P,
    const float* __restrict__ W1, const float* __restrict__ b1,
    const float* __restrict__ W2, const float* __restrict__ b2,
    const float* __restrict__ W3, const float* __restrict__ b3,
    float* __restrict__ out_integ, float* __restrict__ out_knots)
{
    __shared__ float4 s_w2[4096];      // 64 KB, row j at [j*32..j*32+31], swizzled
    __shared__ float s_h1[16][128];    // 8 KB
    __shared__ float s_part[16][2][5]; // per-wave logit partials (2 elems/group)
    __shared__ float LA[16][8][10];
    __shared__ float LQ[16][16];
    __shared__ float LR[16][16];
    __shared__ float s_coef[16][64];

    const int tid = threadIdx.x;
    const int wv = tid >> 6, lane = tid & 63;
    const int p = tid >> 7, row = tid & 127;   // 8 groups x 128 rows
    const int b0 = blockIdx.x * 16;

    // ---------------- stage W2 -> LDS, coalesced + XOR-swizzled ----------------
    {
        const float4* W2v = (const float4*)W2;
        #pragma unroll
        for (int it = 0; it < 4; ++it) {
            int f = it * 1024 + tid;         // float4 index in [0, 4096)
            int j = f >> 5, c4 = f & 31;
            s_w2[j * 32 + (c4 ^ (j & 7))] = W2v[f];
        }
    }

    // ---------------- M1: h1 rows for this group's 2 elements ----------------
    {
        float4 w0 = ((const float4*)(W1 + row * 8))[0];
        float4 w1 = ((const float4*)(W1 + row * 8))[1];
        float bb = b1[row];
        #pragma unroll
        for (int k = 0; k < 2; ++k) {
            const float* xr = x + (b0 + p * 2 + k) * 8;
            float4 xa = ((const float4*)xr)[0];
            float4 xb = ((const float4*)xr)[1];
            float h = bb + w0.x*xa.x + w0.y*xa.y + w0.z*xa.z + w0.w*xa.w
                         + w1.x*xb.x + w1.y*xb.y + w1.z*xb.z + w1.w*xb.w;
            s_h1[p * 2 + k][row] = fmaxf(h, 0.f);
        }
    }
    __syncthreads();   // covers W2 staging + h1 writes

    // ------ M2: h2[row] for 2 elements — W2 from LDS (swizzled) ------
    float bb2 = b2[row];
    float a0 = bb2, a1 = bb2;
    {
        const float4* wrow = s_w2 + row * 32;
        const int rx = row & 7;
        const float4* h0 = (const float4*)s_h1[p * 2 + 0];
        const float4* h1 = (const float4*)s_h1[p * 2 + 1];
        #pragma unroll 8
        for (int c4 = 0; c4 < 32; ++c4) {
            float4 w = wrow[c4 ^ rx];        // undoes storage permutation
            float4 ha = h0[c4], hb = h1[c4];
            a0 += w.x*ha.x + w.y*ha.y + w.z*ha.z + w.w*ha.w;
            a1 += w.x*hb.x + w.y*hb.y + w.z*hb.z + w.w*hb.w;
        }
    }
    float h2_0 = fmaxf(a0, 0.f), h2_1 = fmaxf(a1, 0.f);

    // ---------------- M3: logit partials via DPP (no LDS pipe) ----------------
    #pragma unroll
    for (int c = 0; c < 5; ++c) {
        float wc = W3[c * 128 + row];
        float p0 = wave_sum64(wc * h2_0);
        float p1 = wave_sum64(wc * h2_1);
        if (lane == 0) { s_part[wv][0][c] = p0; s_part[wv][1][c] = p1; }
    }
    __syncthreads();

    // ---------------- prep on waves 0-1: el = wv*8 + (lane>>3) ----------------
    if (wv < 2) {
        const int el = wv * 8 + (lane >> 3), r = lane & 7;
        const int e = b0 + el;
        const int g2 = (el >> 1) * 2, sl = el & 1;   // partial waves g2, g2+1

        float lg0 = s_part[g2][sl][0] + s_part[g2 + 1][sl][0] + b3[0];
        float lg1 = s_part[g2][sl][1] + s_part[g2 + 1][sl][1] + b3[1];
        float lg2 = s_part[g2][sl][2] + s_part[g2 + 1][sl][2] + b3[2];
        float lg3 = s_part[g2][sl][3] + s_part[g2 + 1][sl][3] + b3[3];
        float lg4 = s_part[g2][sl][4] + s_part[g2 + 1][sl][4] + b3[4];
        float mx = fmaxf(fmaxf(fmaxf(fmaxf(lg0, lg1), lg2), lg3), lg4);
        float e0 = expf(lg0-mx), e1 = expf(lg1-mx), e2 = expf(lg2-mx),
              e3 = expf(lg3-mx), e4 = expf(lg4-mx);
        float s = e0 + e1 + e2 + e3 + e4;
        float xs0 = e0/s, xs1 = e1/s, xs2 = e2/s, xs3 = e3/s;
        float c0 = xs0, c1 = c0 + xs1, c2 = c1 + xs2, c3 = c2 + xs3;
        float w4 = xs0 + (c0 - xs0);
        float w5 = xs1 + (c1 - xs1);
        float w6 = xs2 + (c2 - xs2);
        float w7 = xs3 + (c3 - xs3);

        {
            float kv = (r < 4) ? 0.f : (r == 4 ? w4 : r == 5 ? w5 : r == 6 ? w6 : w7);
            out_knots[e * 12 + r] = kv;
            if (r < 4) {
                out_knots[e * 12 + 8 + r] = 1.f;
                s_coef[el][60 + r] = (r == 0 ? w4 : r == 1 ? w5 : r == 2 ? w6 : w7);
            }
        }

        const float ka[12] = {0.f,0.f,0.f,0.f,w4,w5,w6,w7,1.f,1.f,1.f,1.f};
        float t = (r == 2) ? w4 : (r == 3) ? w5 : (r == 4) ? w6 : (r == 5) ? w7 : 0.f;
        float N[11];
        #pragma unroll
        for (int i = 0; i < 11; ++i)
            N[i] = (t >= ka[i] && t < ka[i+1]) ? 1.f : 0.f;
        #pragma unroll
        for (int pq = 1; pq <= 3; ++pq) {
            #pragma unroll
            for (int i = 0; i < 10; ++i) {
                if (i < 10 - pq) {   // m = 10-pq, replicates ref's partial update
                    float da = ka[i+pq] - ka[i];
                    float av = (da != 0.f) ? (t - ka[i]) * frcp(da) : 0.f;
                    float db = ka[i+pq+1] - ka[i+1];
                    float bv = (db != 0.f) ? (ka[i+pq+1] - t) * frcp(db) : 0.f;
                    N[i] = N[i] * av + N[i+1] * bv;
                }
            }
        }

        float a[10];
        #pragma unroll
        for (int c = 0; c < 8; ++c) {
            float v0 = (c==0) ? w5 : (c==1) ? (-w4-w5) : (c==2) ? w4 : 0.f;
            float v6 = (c==7) ? 1.f : 0.f;
            float v7 = (c==5) ? (1.f-w7) : (c==6) ? (w7+w6-2.f) : (c==7) ? (1.f-w6) : 0.f;
            float vb = (r==0) ? v0 : (r==6) ? v6 : v7;
            a[c] = (r >= 1 && r <= 5) ? N[c] : vb;
        }
        {
            float px = 0.f, py = 0.f;
            if (r >= 1 && r <= 6) {
                px = P[e * 12 + (r-1) * 2 + 0];
                py = P[e * 12 + (r-1) * 2 + 1];
            }
            a[8] = px; a[9] = py;
        }

        // GE with partial pivoting: 8-lane groups, proven shfl path
        int done = 0, pcol = 7;
        #pragma unroll
        for (int col = 0; col < 8; ++col) {
            float bv = done ? -1.f : fabsf(a[col]);
            int bi = lane;
            #pragma unroll
            for (int m = 1; m <= 4; m <<= 1) {
                float ov = __shfl_xor(bv, m, 64);
                int   oi = __shfl_xor(bi, m, 64);
                if (ov > bv || (ov == bv && oi < bi)) { bv = ov; bi = oi; }
            }
            float pr[10];
            #pragma unroll
            for (int c = 0; c < 10; ++c) pr[c] = __shfl(a[c], bi, 64);
            if (lane == bi) { done = 1; pcol = col; }
            else if (!done) {
                float f = a[col] * frcp(pr[col]);
                #pragma unroll
                for (int c = 0; c < 10; ++c) if (c > col) a[c] -= f * pr[c];
            }
        }
        #pragma unroll
        for (int c = 0; c < 10; ++c) LA[el][pcol][c] = a[c];
        WSYNC();

        if (r < 2) {
            const int par = r;
            float C[8];
            #pragma unroll
            for (int col = 7; col >= 0; --col) {
                float sv = LA[el][col][8 + par];
                #pragma unroll
                for (int c = col + 1; c < 8; ++c) sv -= LA[el][col][c] * C[c];
                C[col] = sv * frcp(LA[el][col][col]);
            }
            float Qr[7], Rr[6];
            const float dq[7] = { w4, w5, w6, w7 - w4, 1.f - w5, 1.f - w6, 1.f - w7 };
            #pragma unroll
            for (int i = 0; i < 7; ++i) Qr[i] = (3.f * frcp(dq[i])) * (C[i+1] - C[i]);
            const float dr[6] = { w4, w5, w6 - w4, w7 - w5, 1.f - w6, 1.f - w7 };
            #pragma unroll
            for (int i = 0; i < 6; ++i) Rr[i] = (2.f * frcp(dr[i])) * (Qr[i+1] - Qr[i]);
            #pragma unroll
            for (int i = 0; i < 7; ++i) LQ[el][i*2+par] = Qr[i];
            #pragma unroll
            for (int i = 0; i < 6; ++i) LR[el][i*2+par] = Rr[i];
        }
        WSYNC();

        if (r < 5) {
            const int s5 = r;
            float k2 = (s5 <= 1) ? 0.f : (s5 == 2) ? w4 : (s5 == 3) ? w5 : w6;
            float k3 = (s5 == 0) ? 0.f : (s5 == 1) ? w4 : (s5 == 2) ? w5 : (s5 == 3) ? w6 : w7;
            float k4 = (s5 == 0) ? w4 : (s5 == 1) ? w5 : (s5 == 2) ? w6 : (s5 == 3) ? w7 : 1.f;
            float k5 = (s5 == 0) ? w5 : (s5 == 1) ? w6 : (s5 == 2) ? w7 : 1.f;
            float q0x = LQ[el][s5*2],     q0y = LQ[el][s5*2+1];
            float q1x = LQ[el][(s5+1)*2], q1y = LQ[el][(s5+1)*2+1];
            float q2x = LQ[el][(s5+2)*2], q2y = LQ[el][(s5+2)*2+1];
            float r0x = LR[el][s5*2],     r0y = LR[el][s5*2+1];
            float r1x = LR[el][(s5+1)*2], r1y = LR[el][(s5+1)*2+1];
            float r42 = frcp(k4-k2), r53 = frcp(k5-k3), r43 = frcp(k4-k3);
            float A0x = (k4*q0x - k2*q1x)*r42, B0x = (q1x-q0x)*r42;
            float A1x = (k5*q1x - k3*q2x)*r53, B1x = (q2x-q1x)*r53;
            float c0x = r43*(k4*A0x - k3*A1x);
            float c1x = r43*(k4*B0x - A0x + A1x - k3*B1x);
            float c2x = r43*(B1x - B0x);
            float e0x = r43*(k4*r0x - k3*r1x);
            float e1x = r43*(r1x - r0x);
            float A0y = (k4*q0y - k2*q1y)*r42, B0y = (q1y-q0y)*r42;
            float A1y = (k5*q1y - k3*q2y)*r53, B1y = (q2y-q1y)*r53;
            float c0y = r43*(k4*A0y - k3*A1y);
            float c1y = r43*(k4*B0y - A0y + A1y - k3*B1y);
            float c2y = r43*(B1y - B0y);
            float e0y = r43*(k4*r0y - k3*r1y);
            float e1y = r43*(r1y - r0y);
            float* cb = &s_coef[el][s5 * 12];
            cb[0] = c0x; cb[1] = c1x; cb[2]  = c2x; cb[3]  = c0y;
            cb[4] = c1y; cb[5] = c2y; cb[6]  = e0x; cb[7]  = e1x;
            cb[8] = e0y; cb[9] = e1y; cb[10] = 0.f; cb[11] = 0.f;
        }
    }
    __syncthreads();

    // ---------------- eval: wave wv evaluates element b0+wv ----------------
    {
        const int e = b0 + wv;
        const float c999 = 1.f / 999.f;
        float v = s_coef[wv][lane];
        int vi = __float_as_int(v);
        float w4 = __int_as_float(__builtin_amdgcn_readlane(vi, 60));
        float w5 = __int_as_float(__builtin_amdgcn_readlane(vi, 61));
        float w6 = __int_as_float(__builtin_amdgcn_readlane(vi, 62));
        float w7 = __int_as_float(__builtin_amdgcn_readlane(vi, 63));

        auto bsearch = [&](float w) {   // first idx with idx*c999 > w
            int lo = 0, hi = 1000;
            #pragma unroll
            for (int it = 0; it < 10; ++it) {
                int mid = (lo + hi) >> 1;
                bool pr = ((float)mid * c999 > w);
                hi = pr ? mid : hi;
                lo = pr ? lo : (mid + 1);
            }
            return lo;
        };
        int B0 = bsearch(w4), B1 = bsearch(w5), B2 = bsearch(w6), B3 = bsearch(w7);

        float acc = 0.f;
        #define DOSEG(S, LOE, HIE) { \
            float cx0 = __int_as_float(__builtin_amdgcn_readlane(vi, (S)*12+0)); \
            float cx1 = __int_as_float(__builtin_amdgcn_readlane(vi, (S)*12+1)); \
            float cx2 = __int_as_float(__builtin_amdgcn_readlane(vi, (S)*12+2)); \
            float cy0 = __int_as_float(__builtin_amdgcn_readlane(vi, (S)*12+3)); \
            float cy1 = __int_as_float(__builtin_amdgcn_readlane(vi, (S)*12+4)); \
            float cy2 = __int_as_float(__builtin_amdgcn_readlane(vi, (S)*12+5)); \
            float ex0 = __int_as_float(__builtin_amdgcn_readlane(vi, (S)*12+6)); \
            float ex1 = __int_as_float(__builtin_amdgcn_readlane(vi, (S)*12+7)); \
            float ey0 = __int_as_float(__builtin_amdgcn_readlane(vi, (S)*12+8)); \
            float ey1 = __int_as_float(__builtin_amdgcn_readlane(vi, (S)*12+9)); \
            int lo = (LOE), hi = (HIE); \
            float wl = ((lo + lane) & 1) ? 4.f : 2.f; \
            for (int idx = lo + lane; idx < hi; idx += 64) { \
                float tt = (float)idx * c999; \
                float spx = (cx2 * tt + cx1) * tt + cx0; \
                float spy = (cy2 * tt + cy1) * tt + cy0; \
                float sdx = ex1 * tt + ex0; \
                float sdy = ey1 * tt + ey0; \
                float s2 = spx * spx + spy * spy; \
                float cross = spx * sdy - spy * sdx; \
                float rs = rsqrtf(s2); \
                float rs2 = rs * rs; \
                acc += wl * (cross * cross * (rs2 * rs2 * rs)); \
            } }
        DOSEG(0, 0,  B0)
        DOSEG(1, B0, B1)
        DOSEG(2, B1, B2)
        DOSEG(3, B2, B3)
        DOSEG(4, B3, 1000)
        #undef DOSEG

        float total = wave_sum64(acc);   // DPP, no LDS pipe
        if (lane == 0) out_integ[e] = (1.f / 999.f) / 3.f * total;
    }
}

extern "C" void kernel_launch(void* const* d_in, const int* in_sizes, int n_in,
                              void* d_out, int out_size, void* d_ws, size_t ws_size,
                              hipStream_t stream) {
    const float* x  = (const float*)d_in[0];
    const float* P  = (const float*)d_in[1];
    const float* W1 = (const float*)d_in[2];
    const float* b1 = (const float*)d_in[3];
    const float* W2 = (const float*)d_in[4];
    const float* b2 = (const float*)d_in[5];
    const float* W3 = (const float*)d_in[6];
    const float* b3 = (const float*)d_in[7];
    float* out_integ = (float*)d_out;
    float* out_knots = out_integ + BATCH;

    net2_one<<<dim3(BATCH / 16), dim3(1024), 0, stream>>>(
        x, P, W1, b1, W2, b2, W3, b3, out_integ, out_knots);
}

// Round 18
// 24.559 us; speedup vs baseline: 1.0229x; 1.0229x over previous
//
#include <hip/hip_runtime.h>
#include <math.h>

#define BATCH 4096
#define NPTS 1000

// Within-wave LDS producer->consumer fence (LDS ops are memory ops; the
// clobber orders them, sched_barrier stops migration).
#define WSYNC() do { asm volatile("s_waitcnt lgkmcnt(0)" ::: "memory"); \
                     __builtin_amdgcn_sched_barrier(0); } while (0)

// fast 1-ulp reciprocal (v_rcp_f32) — used only downstream of the knots
__device__ __forceinline__ float frcp(float v) { return __builtin_amdgcn_rcpf(v); }

// Full-wave (64-lane) sum via DPP — pure VALU, no LDS pipe (rocPRIM pattern).
__device__ __forceinline__ float wave_sum64(float v) {
    int x = __float_as_int(v), y;
    y = __builtin_amdgcn_update_dpp(0, x, 0x111, 0xF, 0xF, true);   // row_shr:1
    x = __float_as_int(__int_as_float(x) + __int_as_float(y));
    y = __builtin_amdgcn_update_dpp(0, x, 0x112, 0xF, 0xF, true);   // row_shr:2
    x = __float_as_int(__int_as_float(x) + __int_as_float(y));
    y = __builtin_amdgcn_update_dpp(0, x, 0x114, 0xF, 0xF, true);   // row_shr:4
    x = __float_as_int(__int_as_float(x) + __int_as_float(y));
    y = __builtin_amdgcn_update_dpp(0, x, 0x118, 0xF, 0xF, true);   // row_shr:8
    x = __float_as_int(__int_as_float(x) + __int_as_float(y));
    y = __builtin_amdgcn_update_dpp(0, x, 0x142, 0xA, 0xF, false);  // row_bcast:15
    x = __float_as_int(__int_as_float(x) + __int_as_float(y));
    y = __builtin_amdgcn_update_dpp(0, x, 0x143, 0xC, 0xF, false);  // row_bcast:31
    x = __float_as_int(__int_as_float(x) + __int_as_float(y));
    return __int_as_float(__builtin_amdgcn_readlane(x, 63));
}

// ========== 16 elements/block, 512 threads (E=4), 1 block/CU, W2 in LDS ==========
// 4 row-groups x 4-element FMA chains: W2 row-read amortized over 4 elements,
// LDS instruction count -17% vs E=2. Prep on waves 0-1; eval 2 elems/wave.
__global__ __launch_bounds__(512, 4) void net2_one(
    const float* __restrict__ x, const float* __restrict__ P,
    const float* __restrict__ W1, const float* __restrict__ b1,
    const float* __restrict__ W2, const float* __restrict__ b2,
    const float* __restrict__ W3, const float* __restrict__ b3,
    float* __restrict__ out_integ, float* __restrict__ out_knots)
{
    __shared__ float4 s_w2[4096];      // 64 KB, row j at [j*32..j*32+31], swizzled
    __shared__ float s_h1[16][128];    // 8 KB
    __shared__ float s_part[8][4][5];  // per-wave logit partials (4 elems/group)
    __shared__ float LA[16][8][10];
    __shared__ float LQ[16][16];
    __shared__ float LR[16][16];
    __shared__ float s_coef[16][64];

    const int tid = threadIdx.x;
    const int wv = tid >> 6, lane = tid & 63;
    const int p = tid >> 7, row = tid & 127;   // 4 groups x 128 rows
    const int b0 = blockIdx.x * 16;

    // ---------------- stage W2 -> LDS, coalesced + XOR-swizzled ----------------
    {
        const float4* W2v = (const float4*)W2;
        #pragma unroll
        for (int it = 0; it < 8; ++it) {
            int f = it * 512 + tid;          // float4 index in [0, 4096)
            int j = f >> 5, c4 = f & 31;
            s_w2[j * 32 + (c4 ^ (j & 7))] = W2v[f];
        }
    }

    // ---------------- M1: h1 rows for this group's 4 elements ----------------
    {
        float4 w0 = ((const float4*)(W1 + row * 8))[0];
        float4 w1 = ((const float4*)(W1 + row * 8))[1];
        float bb = b1[row];
        #pragma unroll
        for (int k = 0; k < 4; ++k) {
            const float* xr = x + (b0 + p * 4 + k) * 8;
            float4 xa = ((const float4*)xr)[0];
            float4 xb = ((const float4*)xr)[1];
            float h = bb + w0.x*xa.x + w0.y*xa.y + w0.z*xa.z + w0.w*xa.w
                         + w1.x*xb.x + w1.y*xb.y + w1.z*xb.z + w1.w*xb.w;
            s_h1[p * 4 + k][row] = fmaxf(h, 0.f);
        }
    }
    __syncthreads();   // covers W2 staging + h1 writes

    // ------ M2: h2[row] for 4 elements — W2 from LDS (swizzled) ------
    float bb2 = b2[row];
    float a0 = bb2, a1 = bb2, a2 = bb2, a3 = bb2;
    {
        const float4* wrow = s_w2 + row * 32;
        const int rx = row & 7;
        const float4* h0 = (const float4*)s_h1[p * 4 + 0];
        const float4* h1 = (const float4*)s_h1[p * 4 + 1];
        const float4* h2p = (const float4*)s_h1[p * 4 + 2];
        const float4* h3 = (const float4*)s_h1[p * 4 + 3];
        #pragma unroll 8
        for (int c4 = 0; c4 < 32; ++c4) {
            float4 w = wrow[c4 ^ rx];        // undoes storage permutation
            float4 ha = h0[c4], hb = h1[c4], hc = h2p[c4], hd = h3[c4];
            a0 += w.x*ha.x + w.y*ha.y + w.z*ha.z + w.w*ha.w;
            a1 += w.x*hb.x + w.y*hb.y + w.z*hb.z + w.w*hb.w;
            a2 += w.x*hc.x + w.y*hc.y + w.z*hc.z + w.w*hc.w;
            a3 += w.x*hd.x + w.y*hd.y + w.z*hd.z + w.w*hd.w;
        }
    }
    float h2_0 = fmaxf(a0, 0.f), h2_1 = fmaxf(a1, 0.f);
    float h2_2 = fmaxf(a2, 0.f), h2_3 = fmaxf(a3, 0.f);

    // ---------------- M3: logit partials via DPP ----------------
    #pragma unroll
    for (int c = 0; c < 5; ++c) {
        float wc = W3[c * 128 + row];
        float p0 = wave_sum64(wc * h2_0);
        float p1 = wave_sum64(wc * h2_1);
        float p2 = wave_sum64(wc * h2_2);
        float p3 = wave_sum64(wc * h2_3);
        if (lane == 0) {
            s_part[wv][0][c] = p0; s_part[wv][1][c] = p1;
            s_part[wv][2][c] = p2; s_part[wv][3][c] = p3;
        }
    }
    __syncthreads();

    // ---------------- prep on waves 0-1: el = wv*8 + (lane>>3) ----------------
    // element el belongs to group el>>2 (waves 2(el>>2), 2(el>>2)+1), slot el&3
    if (wv < 2) {
        const int el = wv * 8 + (lane >> 3), r = lane & 7;
        const int e = b0 + el;
        const int g2 = (el >> 2) * 2, sl = el & 3;

        float lg0 = s_part[g2][sl][0] + s_part[g2 + 1][sl][0] + b3[0];
        float lg1 = s_part[g2][sl][1] + s_part[g2 + 1][sl][1] + b3[1];
        float lg2 = s_part[g2][sl][2] + s_part[g2 + 1][sl][2] + b3[2];
        float lg3 = s_part[g2][sl][3] + s_part[g2 + 1][sl][3] + b3[3];
        float lg4 = s_part[g2][sl][4] + s_part[g2 + 1][sl][4] + b3[4];
        float mx = fmaxf(fmaxf(fmaxf(fmaxf(lg0, lg1), lg2), lg3), lg4);
        float e0 = expf(lg0-mx), e1 = expf(lg1-mx), e2 = expf(lg2-mx),
              e3 = expf(lg3-mx), e4 = expf(lg4-mx);
        float s = e0 + e1 + e2 + e3 + e4;
        float xs0 = e0/s, xs1 = e1/s, xs2 = e2/s, xs3 = e3/s;
        float c0 = xs0, c1 = c0 + xs1, c2 = c1 + xs2, c3 = c2 + xs3;
        float w4 = xs0 + (c0 - xs0);
        float w5 = xs1 + (c1 - xs1);
        float w6 = xs2 + (c2 - xs2);
        float w7 = xs3 + (c3 - xs3);

        {
            float kv = (r < 4) ? 0.f : (r == 4 ? w4 : r == 5 ? w5 : r == 6 ? w6 : w7);
            out_knots[e * 12 + r] = kv;
            if (r < 4) {
                out_knots[e * 12 + 8 + r] = 1.f;
                s_coef[el][60 + r] = (r == 0 ? w4 : r == 1 ? w5 : r == 2 ? w6 : w7);
            }
        }

        const float ka[12] = {0.f,0.f,0.f,0.f,w4,w5,w6,w7,1.f,1.f,1.f,1.f};
        float t = (r == 2) ? w4 : (r == 3) ? w5 : (r == 4) ? w6 : (r == 5) ? w7 : 0.f;
        float N[11];
        #pragma unroll
        for (int i = 0; i < 11; ++i)
            N[i] = (t >= ka[i] && t < ka[i+1]) ? 1.f : 0.f;
        #pragma unroll
        for (int pq = 1; pq <= 3; ++pq) {
            #pragma unroll
            for (int i = 0; i < 10; ++i) {
                if (i < 10 - pq) {   // m = 10-pq, replicates ref's partial update
                    float da = ka[i+pq] - ka[i];
                    float av = (da != 0.f) ? (t - ka[i]) * frcp(da) : 0.f;
                    float db = ka[i+pq+1] - ka[i+1];
                    float bv = (db != 0.f) ? (ka[i+pq+1] - t) * frcp(db) : 0.f;
                    N[i] = N[i] * av + N[i+1] * bv;
                }
            }
        }

        float a[10];
        #pragma unroll
        for (int c = 0; c < 8; ++c) {
            float v0 = (c==0) ? w5 : (c==1) ? (-w4-w5) : (c==2) ? w4 : 0.f;
            float v6 = (c==7) ? 1.f : 0.f;
            float v7 = (c==5) ? (1.f-w7) : (c==6) ? (w7+w6-2.f) : (c==7) ? (1.f-w6) : 0.f;
            float vb = (r==0) ? v0 : (r==6) ? v6 : v7;
            a[c] = (r >= 1 && r <= 5) ? N[c] : vb;
        }
        {
            float px = 0.f, py = 0.f;
            if (r >= 1 && r <= 6) {
                px = P[e * 12 + (r-1) * 2 + 0];
                py = P[e * 12 + (r-1) * 2 + 1];
            }
            a[8] = px; a[9] = py;
        }

        // GE with partial pivoting: 8-lane groups, proven shfl path
        int done = 0, pcol = 7;
        #pragma unroll
        for (int col = 0; col < 8; ++col) {
            float bv = done ? -1.f : fabsf(a[col]);
            int bi = lane;
            #pragma unroll
            for (int m = 1; m <= 4; m <<= 1) {
                float ov = __shfl_xor(bv, m, 64);
                int   oi = __shfl_xor(bi, m, 64);
                if (ov > bv || (ov == bv && oi < bi)) { bv = ov; bi = oi; }
            }
            float pr[10];
            #pragma unroll
            for (int c = 0; c < 10; ++c) pr[c] = __shfl(a[c], bi, 64);
            if (lane == bi) { done = 1; pcol = col; }
            else if (!done) {
                float f = a[col] * frcp(pr[col]);
                #pragma unroll
                for (int c = 0; c < 10; ++c) if (c > col) a[c] -= f * pr[c];
            }
        }
        #pragma unroll
        for (int c = 0; c < 10; ++c) LA[el][pcol][c] = a[c];
        WSYNC();

        if (r < 2) {
            const int par = r;
            float C[8];
            #pragma unroll
            for (int col = 7; col >= 0; --col) {
                float sv = LA[el][col][8 + par];
                #pragma unroll
                for (int c = col + 1; c < 8; ++c) sv -= LA[el][col][c] * C[c];
                C[col] = sv * frcp(LA[el][col][col]);
            }
            float Qr[7], Rr[6];
            const float dq[7] = { w4, w5, w6, w7 - w4, 1.f - w5, 1.f - w6, 1.f - w7 };
            #pragma unroll
            for (int i = 0; i < 7; ++i) Qr[i] = (3.f * frcp(dq[i])) * (C[i+1] - C[i]);
            const float dr[6] = { w4, w5, w6 - w4, w7 - w5, 1.f - w6, 1.f - w7 };
            #pragma unroll
            for (int i = 0; i < 6; ++i) Rr[i] = (2.f * frcp(dr[i])) * (Qr[i+1] - Qr[i]);
            #pragma unroll
            for (int i = 0; i < 7; ++i) LQ[el][i*2+par] = Qr[i];
            #pragma unroll
            for (int i = 0; i < 6; ++i) LR[el][i*2+par] = Rr[i];
        }
        WSYNC();

        if (r < 5) {
            const int s5 = r;
            float k2 = (s5 <= 1) ? 0.f : (s5 == 2) ? w4 : (s5 == 3) ? w5 : w6;
            float k3 = (s5 == 0) ? 0.f : (s5 == 1) ? w4 : (s5 == 2) ? w5 : (s5 == 3) ? w6 : w7;
            float k4 = (s5 == 0) ? w4 : (s5 == 1) ? w5 : (s5 == 2) ? w6 : (s5 == 3) ? w7 : 1.f;
            float k5 = (s5 == 0) ? w5 : (s5 == 1) ? w6 : (s5 == 2) ? w7 : 1.f;
            float q0x = LQ[el][s5*2],     q0y = LQ[el][s5*2+1];
            float q1x = LQ[el][(s5+1)*2], q1y = LQ[el][(s5+1)*2+1];
            float q2x = LQ[el][(s5+2)*2], q2y = LQ[el][(s5+2)*2+1];
            float r0x = LR[el][s5*2],     r0y = LR[el][s5*2+1];
            float r1x = LR[el][(s5+1)*2], r1y = LR[el][(s5+1)*2+1];
            float r42 = frcp(k4-k2), r53 = frcp(k5-k3), r43 = frcp(k4-k3);
            float A0x = (k4*q0x - k2*q1x)*r42, B0x = (q1x-q0x)*r42;
            float A1x = (k5*q1x - k3*q2x)*r53, B1x = (q2x-q1x)*r53;
            float c0x = r43*(k4*A0x - k3*A1x);
            float c1x = r43*(k4*B0x - A0x + A1x - k3*B1x);
            float c2x = r43*(B1x - B0x);
            float e0x = r43*(k4*r0x - k3*r1x);
            float e1x = r43*(r1x - r0x);
            float A0y = (k4*q0y - k2*q1y)*r42, B0y = (q1y-q0y)*r42;
            float A1y = (k5*q1y - k3*q2y)*r53, B1y = (q2y-q1y)*r53;
            float c0y = r43*(k4*A0y - k3*A1y);
            float c1y = r43*(k4*B0y - A0y + A1y - k3*B1y);
            float c2y = r43*(B1y - B0y);
            float e0y = r43*(k4*r0y - k3*r1y);
            float e1y = r43*(r1y - r0y);
            float* cb = &s_coef[el][s5 * 12];
            cb[0] = c0x; cb[1] = c1x; cb[2]  = c2x; cb[3]  = c0y;
            cb[4] = c1y; cb[5] = c2y; cb[6]  = e0x; cb[7]  = e1x;
            cb[8] = e0y; cb[9] = e1y; cb[10] = 0.f; cb[11] = 0.f;
        }
    }
    __syncthreads();

    // ---------------- eval: each wave evaluates 2 elements ----------------
    const float c999 = 1.f / 999.f;
    #pragma unroll
    for (int q = 0; q < 2; ++q) {
        const int el = wv * 2 + q;
        const int e = b0 + el;
        float v = s_coef[el][lane];
        int vi = __float_as_int(v);
        float w4 = __int_as_float(__builtin_amdgcn_readlane(vi, 60));
        float w5 = __int_as_float(__builtin_amdgcn_readlane(vi, 61));
        float w6 = __int_as_float(__builtin_amdgcn_readlane(vi, 62));
        float w7 = __int_as_float(__builtin_amdgcn_readlane(vi, 63));

        auto bsearch = [&](float w) {   // first idx with idx*c999 > w
            int lo = 0, hi = 1000;
            #pragma unroll
            for (int it = 0; it < 10; ++it) {
                int mid = (lo + hi) >> 1;
                bool pr = ((float)mid * c999 > w);
                hi = pr ? mid : hi;
                lo = pr ? lo : (mid + 1);
            }
            return lo;
        };
        int B0 = bsearch(w4), B1 = bsearch(w5), B2 = bsearch(w6), B3 = bsearch(w7);

        float acc = 0.f;
        #define DOSEG(S, LOE, HIE) { \
            float cx0 = __int_as_float(__builtin_amdgcn_readlane(vi, (S)*12+0)); \
            float cx1 = __int_as_float(__builtin_amdgcn_readlane(vi, (S)*12+1)); \
            float cx2 = __int_as_float(__builtin_amdgcn_readlane(vi, (S)*12+2)); \
            float cy0 = __int_as_float(__builtin_amdgcn_readlane(vi, (S)*12+3)); \
            float cy1 = __int_as_float(__builtin_amdgcn_readlane(vi, (S)*12+4)); \
            float cy2 = __int_as_float(__builtin_amdgcn_readlane(vi, (S)*12+5)); \
            float ex0 = __int_as_float(__builtin_amdgcn_readlane(vi, (S)*12+6)); \
            float ex1 = __int_as_float(__builtin_amdgcn_readlane(vi, (S)*12+7)); \
            float ey0 = __int_as_float(__builtin_amdgcn_readlane(vi, (S)*12+8)); \
            float ey1 = __int_as_float(__builtin_amdgcn_readlane(vi, (S)*12+9)); \
            int lo = (LOE), hi = (HIE); \
            float wl = ((lo + lane) & 1) ? 4.f : 2.f; \
            for (int idx = lo + lane; idx < hi; idx += 64) { \
                float tt = (float)idx * c999; \
                float spx = (cx2 * tt + cx1) * tt + cx0; \
                float spy = (cy2 * tt + cy1) * tt + cy0; \
                float sdx = ex1 * tt + ex0; \
                float sdy = ey1 * tt + ey0; \
                float s2 = spx * spx + spy * spy; \
                float cross = spx * sdy - spy * sdx; \
                float rs = rsqrtf(s2); \
                float rs2 = rs * rs; \
                acc += wl * (cross * cross * (rs2 * rs2 * rs)); \
            } }
        DOSEG(0, 0,  B0)
        DOSEG(1, B0, B1)
        DOSEG(2, B1, B2)
        DOSEG(3, B2, B3)
        DOSEG(4, B3, 1000)
        #undef DOSEG

        float total = wave_sum64(acc);
        if (lane == 0) out_integ[e] = (1.f / 999.f) / 3.f * total;
    }
}

extern "C" void kernel_launch(void* const* d_in, const int* in_sizes, int n_in,
                              void* d_out, int out_size, void* d_ws, size_t ws_size,
                              hipStream_t stream) {
    const float* x  = (const float*)d_in[0];
    const float* P  = (const float*)d_in[1];
    const float* W1 = (const float*)d_in[2];
    const float* b1 = (const float*)d_in[3];
    const float* W2 = (const float*)d_in[4];
    const float* b2 = (const float*)d_in[5];
    const float* W3 = (const float*)d_in[6];
    const float* b3 = (const float*)d_in[7];
    float* out_integ = (float*)d_out;
    float* out_knots = out_integ + BATCH;

    net2_one<<<dim3(BATCH / 16), dim3(512), 0, stream>>>(
        x, P, W1, b1, W2, b2, W3, b3, out_integ, out_knots);
}

// Round 19
// 24.466 us; speedup vs baseline: 1.0268x; 1.0038x over previous
//
#include <hip/hip_runtime.h>
#include <math.h>

#define BATCH 4096
#define NPTS 1000

// Within-wave LDS producer->consumer fence (LDS ops are memory ops; the
// clobber orders them, sched_barrier stops migration).
#define WSYNC() do { asm volatile("s_waitcnt lgkmcnt(0)" ::: "memory"); \
                     __builtin_amdgcn_sched_barrier(0); } while (0)

// fast 1-ulp reciprocal (v_rcp_f32) — used only downstream of the knots
__device__ __forceinline__ float frcp(float v) { return __builtin_amdgcn_rcpf(v); }

// read lane `c` (compile-time constant) of a float register across the wave
#define RLANE(reg, c) __int_as_float(__builtin_amdgcn_readlane(__float_as_int(reg), (c)))

// Full-wave (64-lane) sum via DPP — pure VALU, no LDS pipe (rocPRIM pattern).
__device__ __forceinline__ float wave_sum64(float v) {
    int x = __float_as_int(v), y;
    y = __builtin_amdgcn_update_dpp(0, x, 0x111, 0xF, 0xF, true);   // row_shr:1
    x = __float_as_int(__int_as_float(x) + __int_as_float(y));
    y = __builtin_amdgcn_update_dpp(0, x, 0x112, 0xF, 0xF, true);   // row_shr:2
    x = __float_as_int(__int_as_float(x) + __int_as_float(y));
    y = __builtin_amdgcn_update_dpp(0, x, 0x114, 0xF, 0xF, true);   // row_shr:4
    x = __float_as_int(__int_as_float(x) + __int_as_float(y));
    y = __builtin_amdgcn_update_dpp(0, x, 0x118, 0xF, 0xF, true);   // row_shr:8
    x = __float_as_int(__int_as_float(x) + __int_as_float(y));
    y = __builtin_amdgcn_update_dpp(0, x, 0x142, 0xA, 0xF, false);  // row_bcast:15
    x = __float_as_int(__int_as_float(x) + __int_as_float(y));
    y = __builtin_amdgcn_update_dpp(0, x, 0x143, 0xC, 0xF, false);  // row_bcast:31
    x = __float_as_int(__int_as_float(x) + __int_as_float(y));
    return __int_as_float(__builtin_amdgcn_readlane(x, 63));
}

// ========== 16 elements/block, 512 threads (E=4), 1 block/CU, W2 in LDS ==========
// M2's h-operand comes from REGISTERS via readlane (wave-uniform, compile-time
// lane index) instead of LDS broadcast reads: 160 -> 36 LDS instrs per wave.
__global__ __launch_bounds__(512, 4) void net2_one(
    const float* __restrict__ x, const float* __restrict__ P,
    const float* __restrict__ W1, const float* __restrict__ b1,
    const float* __restrict__ W2, const float* __restrict__ b2,
    const float* __restrict__ W3, const float* __restrict__ b3,
    float* __restrict__ out_integ, float* __restrict__ out_knots)
{
    __shared__ float4 s_w2[4096];      // 64 KB, row j at [j*32..j*32+31], swizzled
    __shared__ float s_h1[16][128];    // 8 KB
    __shared__ float s_part[8][4][5];  // per-wave logit partials (4 elems/group)
    __shared__ float LA[16][8][10];
    __shared__ float LQ[16][16];
    __shared__ float LR[16][16];
    __shared__ float s_coef[16][64];

    const int tid = threadIdx.x;
    const int wv = tid >> 6, lane = tid & 63;
    const int p = tid >> 7, row = tid & 127;   // 4 groups x 128 rows
    const int b0 = blockIdx.x * 16;

    // ---------------- stage W2 -> LDS, coalesced + XOR-swizzled ----------------
    {
        const float4* W2v = (const float4*)W2;
        #pragma unroll
        for (int it = 0; it < 8; ++it) {
            int f = it * 512 + tid;          // float4 index in [0, 4096)
            int j = f >> 5, c4 = f & 31;
            s_w2[j * 32 + (c4 ^ (j & 7))] = W2v[f];
        }
    }

    // ------- M1: h1 rows for this group's 4 elements (keep own values in regs) -------
    float hOwn0, hOwn1, hOwn2, hOwn3;
    {
        float4 w0 = ((const float4*)(W1 + row * 8))[0];
        float4 w1 = ((const float4*)(W1 + row * 8))[1];
        float bb = b1[row];
        #pragma unroll
        for (int k = 0; k < 4; ++k) {
            const float* xr = x + (b0 + p * 4 + k) * 8;
            float4 xa = ((const float4*)xr)[0];
            float4 xb = ((const float4*)xr)[1];
            float h = bb + w0.x*xa.x + w0.y*xa.y + w0.z*xa.z + w0.w*xa.w
                         + w1.x*xb.x + w1.y*xb.y + w1.z*xb.z + w1.w*xb.w;
            h = fmaxf(h, 0.f);
            s_h1[p * 4 + k][row] = h;
            if (k == 0) hOwn0 = h; else if (k == 1) hOwn1 = h;
            else if (k == 2) hOwn2 = h; else hOwn3 = h;
        }
    }
    __syncthreads();   // covers W2 staging + h1 writes

    // ------ M2: h2[row] for 4 elements — h from registers via readlane ------
    float bb2 = b2[row];
    float a0 = bb2, a1 = bb2, a2 = bb2, a3 = bb2;
    {
        const int hf = wv & 1;               // which half of rows this wave owns
        const int ob = (1 - hf) * 64;        // other half base
        float t0 = s_h1[p * 4 + 0][ob + lane];
        float t1 = s_h1[p * 4 + 1][ob + lane];
        float t2 = s_h1[p * 4 + 2][ob + lane];
        float t3 = s_h1[p * 4 + 3][ob + lane];
        // hL*: h1[el][lane] (rows 0-63); hH*: h1[el][64+lane] (rows 64-127)
        float hL0 = hf ? t0 : hOwn0, hH0 = hf ? hOwn0 : t0;
        float hL1 = hf ? t1 : hOwn1, hH1 = hf ? hOwn1 : t1;
        float hL2 = hf ? t2 : hOwn2, hH2 = hf ? hOwn2 : t2;
        float hL3 = hf ? t3 : hOwn3, hH3 = hf ? hOwn3 : t3;

        const float4* wrow = s_w2 + row * 32;
        const int rx = row & 7;
        #pragma unroll
        for (int c4 = 0; c4 < 32; ++c4) {
            float4 w = wrow[c4 ^ rx];        // undoes storage permutation
            #pragma unroll
            for (int j = 0; j < 4; ++j) {
                const int c = c4 * 4 + j;
                float wj = (j == 0) ? w.x : (j == 1) ? w.y : (j == 2) ? w.z : w.w;
                float h0v, h1v, h2v, h3v;
                if (c < 64) {
                    h0v = RLANE(hL0, c); h1v = RLANE(hL1, c);
                    h2v = RLANE(hL2, c); h3v = RLANE(hL3, c);
                } else {
                    h0v = RLANE(hH0, c - 64); h1v = RLANE(hH1, c - 64);
                    h2v = RLANE(hH2, c - 64); h3v = RLANE(hH3, c - 64);
                }
                a0 += wj * h0v; a1 += wj * h1v;
                a2 += wj * h2v; a3 += wj * h3v;
            }
        }
    }
    float h2_0 = fmaxf(a0, 0.f), h2_1 = fmaxf(a1, 0.f);
    float h2_2 = fmaxf(a2, 0.f), h2_3 = fmaxf(a3, 0.f);

    // ---------------- M3: logit partials via DPP ----------------
    #pragma unroll
    for (int c = 0; c < 5; ++c) {
        float wc = W3[c * 128 + row];
        float p0 = wave_sum64(wc * h2_0);
        float p1 = wave_sum64(wc * h2_1);
        float p2 = wave_sum64(wc * h2_2);
        float p3 = wave_sum64(wc * h2_3);
        if (lane == 0) {
            s_part[wv][0][c] = p0; s_part[wv][1][c] = p1;
            s_part[wv][2][c] = p2; s_part[wv][3][c] = p3;
        }
    }
    __syncthreads();

    // ---------------- prep on waves 0-1: el = wv*8 + (lane>>3) ----------------
    if (wv < 2) {
        const int el = wv * 8 + (lane >> 3), r = lane & 7;
        const int e = b0 + el;
        const int g2 = (el >> 2) * 2, sl = el & 3;

        float lg0 = s_part[g2][sl][0] + s_part[g2 + 1][sl][0] + b3[0];
        float lg1 = s_part[g2][sl][1] + s_part[g2 + 1][sl][1] + b3[1];
        float lg2 = s_part[g2][sl][2] + s_part[g2 + 1][sl][2] + b3[2];
        float lg3 = s_part[g2][sl][3] + s_part[g2 + 1][sl][3] + b3[3];
        float lg4 = s_part[g2][sl][4] + s_part[g2 + 1][sl][4] + b3[4];
        float mx = fmaxf(fmaxf(fmaxf(fmaxf(lg0, lg1), lg2), lg3), lg4);
        float e0 = expf(lg0-mx), e1 = expf(lg1-mx), e2 = expf(lg2-mx),
              e3 = expf(lg3-mx), e4 = expf(lg4-mx);
        float s = e0 + e1 + e2 + e3 + e4;
        float xs0 = e0/s, xs1 = e1/s, xs2 = e2/s, xs3 = e3/s;
        float c0 = xs0, c1 = c0 + xs1, c2 = c1 + xs2, c3 = c2 + xs3;
        float w4 = xs0 + (c0 - xs0);
        float w5 = xs1 + (c1 - xs1);
        float w6 = xs2 + (c2 - xs2);
        float w7 = xs3 + (c3 - xs3);

        {
            float kv = (r < 4) ? 0.f : (r == 4 ? w4 : r == 5 ? w5 : r == 6 ? w6 : w7);
            out_knots[e * 12 + r] = kv;
            if (r < 4) {
                out_knots[e * 12 + 8 + r] = 1.f;
                s_coef[el][60 + r] = (r == 0 ? w4 : r == 1 ? w5 : r == 2 ? w6 : w7);
            }
        }

        const float ka[12] = {0.f,0.f,0.f,0.f,w4,w5,w6,w7,1.f,1.f,1.f,1.f};
        float t = (r == 2) ? w4 : (r == 3) ? w5 : (r == 4) ? w6 : (r == 5) ? w7 : 0.f;
        float N[11];
        #pragma unroll
        for (int i = 0; i < 11; ++i)
            N[i] = (t >= ka[i] && t < ka[i+1]) ? 1.f : 0.f;
        #pragma unroll
        for (int pq = 1; pq <= 3; ++pq) {
            #pragma unroll
            for (int i = 0; i < 10; ++i) {
                if (i < 10 - pq) {   // m = 10-pq, replicates ref's partial update
                    float da = ka[i+pq] - ka[i];
                    float av = (da != 0.f) ? (t - ka[i]) * frcp(da) : 0.f;
                    float db = ka[i+pq+1] - ka[i+1];
                    float bv = (db != 0.f) ? (ka[i+pq+1] - t) * frcp(db) : 0.f;
                    N[i] = N[i] * av + N[i+1] * bv;
                }
            }
        }

        float a[10];
        #pragma unroll
        for (int c = 0; c < 8; ++c) {
            float v0 = (c==0) ? w5 : (c==1) ? (-w4-w5) : (c==2) ? w4 : 0.f;
            float v6 = (c==7) ? 1.f : 0.f;
            float v7 = (c==5) ? (1.f-w7) : (c==6) ? (w7+w6-2.f) : (c==7) ? (1.f-w6) : 0.f;
            float vb = (r==0) ? v0 : (r==6) ? v6 : v7;
            a[c] = (r >= 1 && r <= 5) ? N[c] : vb;
        }
        {
            float px = 0.f, py = 0.f;
            if (r >= 1 && r <= 6) {
                px = P[e * 12 + (r-1) * 2 + 0];
                py = P[e * 12 + (r-1) * 2 + 1];
            }
            a[8] = px; a[9] = py;
        }

        // GE with partial pivoting: 8-lane groups, proven shfl path
        int done = 0, pcol = 7;
        #pragma unroll
        for (int col = 0; col < 8; ++col) {
            float bv = done ? -1.f : fabsf(a[col]);
            int bi = lane;
            #pragma unroll
            for (int m = 1; m <= 4; m <<= 1) {
                float ov = __shfl_xor(bv, m, 64);
                int   oi = __shfl_xor(bi, m, 64);
                if (ov > bv || (ov == bv && oi < bi)) { bv = ov; bi = oi; }
            }
            float pr[10];
            #pragma unroll
            for (int c = 0; c < 10; ++c) pr[c] = __shfl(a[c], bi, 64);
            if (lane == bi) { done = 1; pcol = col; }
            else if (!done) {
                float f = a[col] * frcp(pr[col]);
                #pragma unroll
                for (int c = 0; c < 10; ++c) if (c > col) a[c] -= f * pr[c];
            }
        }
        #pragma unroll
        for (int c = 0; c < 10; ++c) LA[el][pcol][c] = a[c];
        WSYNC();

        if (r < 2) {
            const int par = r;
            float C[8];
            #pragma unroll
            for (int col = 7; col >= 0; --col) {
                float sv = LA[el][col][8 + par];
                #pragma unroll
                for (int c = col + 1; c < 8; ++c) sv -= LA[el][col][c] * C[c];
                C[col] = sv * frcp(LA[el][col][col]);
            }
            float Qr[7], Rr[6];
            const float dq[7] = { w4, w5, w6, w7 - w4, 1.f - w5, 1.f - w6, 1.f - w7 };
            #pragma unroll
            for (int i = 0; i < 7; ++i) Qr[i] = (3.f * frcp(dq[i])) * (C[i+1] - C[i]);
            const float dr[6] = { w4, w5, w6 - w4, w7 - w5, 1.f - w6, 1.f - w7 };
            #pragma unroll
            for (int i = 0; i < 6; ++i) Rr[i] = (2.f * frcp(dr[i])) * (Qr[i+1] - Qr[i]);
            #pragma unroll
            for (int i = 0; i < 7; ++i) LQ[el][i*2+par] = Qr[i];
            #pragma unroll
            for (int i = 0; i < 6; ++i) LR[el][i*2+par] = Rr[i];
        }
        WSYNC();

        if (r < 5) {
            const int s5 = r;
            float k2 = (s5 <= 1) ? 0.f : (s5 == 2) ? w4 : (s5 == 3) ? w5 : w6;
            float k3 = (s5 == 0) ? 0.f : (s5 == 1) ? w4 : (s5 == 2) ? w5 : (s5 == 3) ? w6 : w7;
            float k4 = (s5 == 0) ? w4 : (s5 == 1) ? w5 : (s5 == 2) ? w6 : (s5 == 3) ? w7 : 1.f;
            float k5 = (s5 == 0) ? w5 : (s5 == 1) ? w6 : (s5 == 2) ? w7 : 1.f;
            float q0x = LQ[el][s5*2],     q0y = LQ[el][s5*2+1];
            float q1x = LQ[el][(s5+1)*2], q1y = LQ[el][(s5+1)*2+1];
            float q2x = LQ[el][(s5+2)*2], q2y = LQ[el][(s5+2)*2+1];
            float r0x = LR[el][s5*2],     r0y = LR[el][s5*2+1];
            float r1x = LR[el][(s5+1)*2], r1y = LR[el][(s5+1)*2+1];
            float r42 = frcp(k4-k2), r53 = frcp(k5-k3), r43 = frcp(k4-k3);
            float A0x = (k4*q0x - k2*q1x)*r42, B0x = (q1x-q0x)*r42;
            float A1x = (k5*q1x - k3*q2x)*r53, B1x = (q2x-q1x)*r53;
            float c0x = r43*(k4*A0x - k3*A1x);
            float c1x = r43*(k4*B0x - A0x + A1x - k3*B1x);
            float c2x = r43*(B1x - B0x);
            float e0x = r43*(k4*r0x - k3*r1x);
            float e1x = r43*(r1x - r0x);
            float A0y = (k4*q0y - k2*q1y)*r42, B0y = (q1y-q0y)*r42;
            float A1y = (k5*q1y - k3*q2y)*r53, B1y = (q2y-q1y)*r53;
            float c0y = r43*(k4*A0y - k3*A1y);
            float c1y = r43*(k4*B0y - A0y + A1y - k3*B1y);
            float c2y = r43*(B1y - B0y);
            float e0y = r43*(k4*r0y - k3*r1y);
            float e1y = r43*(r1y - r0y);
            float* cb = &s_coef[el][s5 * 12];
            cb[0] = c0x; cb[1] = c1x; cb[2]  = c2x; cb[3]  = c0y;
            cb[4] = c1y; cb[5] = c2y; cb[6]  = e0x; cb[7]  = e1x;
            cb[8] = e0y; cb[9] = e1y; cb[10] = 0.f; cb[11] = 0.f;
        }
    }
    __syncthreads();

    // ---------------- eval: each wave evaluates 2 elements ----------------
    const float c999 = 1.f / 999.f;
    #pragma unroll
    for (int q = 0; q < 2; ++q) {
        const int el = wv * 2 + q;
        const int e = b0 + el;
        float v = s_coef[el][lane];
        int vi = __float_as_int(v);
        float w4 = __int_as_float(__builtin_amdgcn_readlane(vi, 60));
        float w5 = __int_as_float(__builtin_amdgcn_readlane(vi, 61));
        float w6 = __int_as_float(__builtin_amdgcn_readlane(vi, 62));
        float w7 = __int_as_float(__builtin_amdgcn_readlane(vi, 63));

        auto bsearch = [&](float w) {   // first idx with idx*c999 > w
            int lo = 0, hi = 1000;
            #pragma unroll
            for (int it = 0; it < 10; ++it) {
                int mid = (lo + hi) >> 1;
                bool pr = ((float)mid * c999 > w);
                hi = pr ? mid : hi;
                lo = pr ? lo : (mid + 1);
            }
            return lo;
        };
        int B0 = bsearch(w4), B1 = bsearch(w5), B2 = bsearch(w6), B3 = bsearch(w7);

        float acc = 0.f;
        #define DOSEG(S, LOE, HIE) { \
            float cx0 = __int_as_float(__builtin_amdgcn_readlane(vi, (S)*12+0)); \
            float cx1 = __int_as_float(__builtin_amdgcn_readlane(vi, (S)*12+1)); \
            float cx2 = __int_as_float(__builtin_amdgcn_readlane(vi, (S)*12+2)); \
            float cy0 = __int_as_float(__builtin_amdgcn_readlane(vi, (S)*12+3)); \
            float cy1 = __int_as_float(__builtin_amdgcn_readlane(vi, (S)*12+4)); \
            float cy2 = __int_as_float(__builtin_amdgcn_readlane(vi, (S)*12+5)); \
            float ex0 = __int_as_float(__builtin_amdgcn_readlane(vi, (S)*12+6)); \
            float ex1 = __int_as_float(__builtin_amdgcn_readlane(vi, (S)*12+7)); \
            float ey0 = __int_as_float(__builtin_amdgcn_readlane(vi, (S)*12+8)); \
            float ey1 = __int_as_float(__builtin_amdgcn_readlane(vi, (S)*12+9)); \
            int lo = (LOE), hi = (HIE); \
            float wl = ((lo + lane) & 1) ? 4.f : 2.f; \
            for (int idx = lo + lane; idx < hi; idx += 64) { \
                float tt = (float)idx * c999; \
                float spx = (cx2 * tt + cx1) * tt + cx0; \
                float spy = (cy2 * tt + cy1) * tt + cy0; \
                float sdx = ex1 * tt + ex0; \
                float sdy = ey1 * tt + ey0; \
                float s2 = spx * spx + spy * spy; \
                float cross = spx * sdy - spy * sdx; \
                float rs = rsqrtf(s2); \
                float rs2 = rs * rs; \
                acc += wl * (cross * cross * (rs2 * rs2 * rs)); \
            } }
        DOSEG(0, 0,  B0)
        DOSEG(1, B0, B1)
        DOSEG(2, B1, B2)
        DOSEG(3, B2, B3)
        DOSEG(4, B3, 1000)
        #undef DOSEG

        float total = wave_sum64(acc);
        if (lane == 0) out_integ[e] = (1.f / 999.f) / 3.f * total;
    }
}

extern "C" void kernel_launch(void* const* d_in, const int* in_sizes, int n_in,
                              void* d_out, int out_size, void* d_ws, size_t ws_size,
                              hipStream_t stream) {
    const float* x  = (const float*)d_in[0];
    const float* P  = (const float*)d_in[1];
    const float* W1 = (const float*)d_in[2];
    const float* b1 = (const float*)d_in[3];
    const float* W2 = (const float*)d_in[4];
    const float* b2 = (const float*)d_in[5];
    const float* W3 = (const float*)d_in[6];
    const float* b3 = (const float*)d_in[7];
    float* out_integ = (float*)d_out;
    float* out_knots = out_integ + BATCH;

    net2_one<<<dim3(BATCH / 16), dim3(512), 0, stream>>>(
        x, P, W1, b1, W2, b2, W3, b3, out_integ, out_knots);
}